// Round 1
// baseline (1649.426 us; speedup 1.0000x reference)
//
#include <hip/hip_runtime.h>
#include <math.h>

#define NB 2
#define U1c 128
#define U2c 32
#define G1 384   // 3*U1
#define G2 96    // 3*U2
#define TT 1024

__device__ __forceinline__ float sigmoidf_(float x) {
    return 1.0f / (1.0f + expf(-x));
}

// 256 blocks x 512 threads. Block owns batches {2b, 2b+1}.
// Threads 0..383: GRU1 gate-lane (rk1 column resident in 128 VGPRs).
// Threads 384..479: GRU2 gate-lane (k2 column 128 VGPR + rk2 column 32 VGPR),
//                   lagged one step behind GRU1 (2 barriers/step pipeline).
// Threads 0..255 also do the h1 update; 256..319 do the h2 update.
__global__ __launch_bounds__(512, 2)
void gru_stack_kernel(const float* __restrict__ x,   // [512,1024,1]
                      const float* __restrict__ k1,  // [1,384]
                      const float* __restrict__ rk1, // [128,384]
                      const float* __restrict__ b1,  // [2,384]
                      const float* __restrict__ k2,  // [128,96]
                      const float* __restrict__ rk2, // [32,96]
                      const float* __restrict__ b2,  // [2,96]
                      const float* __restrict__ wd,  // [32,1]
                      const float* __restrict__ bd,  // [1]
                      float* __restrict__ out)       // [512,1]
{
    __shared__ __align__(16) float h1s[NB][U1c];
    __shared__ __align__(16) float h2s[NB][U2c];
    __shared__ __align__(16) float zr1s[NB][2 * U1c];
    __shared__ __align__(16) float ih1s[NB][U1c];
    __shared__ __align__(16) float xh1s[NB][U1c];
    __shared__ __align__(16) float zr2s[NB][2 * U2c];
    __shared__ __align__(16) float ih2s[NB][U2c];
    __shared__ __align__(16) float xh2s[NB][U2c];

    const int t  = threadIdx.x;
    const int b0 = blockIdx.x * NB;

    // zero-init recurrent state (LDS is uninitialized every launch)
    if (t < NB * U1c) ((float*)h1s)[t] = 0.0f;
    if (t < NB * U2c) ((float*)h2s)[t] = 0.0f;

    if (t < G1) {
        // ------------------------------------------------ GRU1 gate role
        const int g = t;
        float w[U1c];
#pragma unroll
        for (int u = 0; u < U1c; ++u) w[u] = rk1[u * G1 + g];
        const float k1g  = k1[g];
        const float bin  = b1[g];
        const float brec = b1[G1 + g];

        __syncthreads();  // B0: h init visible

        for (int i = 0; i <= TT; ++i) {
            float xv0 = 0.0f, xv1 = 0.0f;
            if (i < TT) {
                // broadcast global load (same addr across wave, L1-resident)
                xv0 = x[(b0 + 0) * TT + i];
                xv1 = x[(b0 + 1) * TT + i];
            }
            if (i < TT) {
                // inner[b][g] = sum_u h1[b][u] * rk1[u][g]
                float a0e = 0.f, a0o = 0.f, a1e = 0.f, a1o = 0.f;
                const float4* h40 = (const float4*)&h1s[0][0];
                const float4* h41 = (const float4*)&h1s[1][0];
#pragma unroll
                for (int u4 = 0; u4 < U1c / 4; ++u4) {
                    float4 a = h40[u4];
                    float4 c = h41[u4];
                    a0e = fmaf(a.x, w[4 * u4 + 0], a0e);
                    a0o = fmaf(a.y, w[4 * u4 + 1], a0o);
                    a0e = fmaf(a.z, w[4 * u4 + 2], a0e);
                    a0o = fmaf(a.w, w[4 * u4 + 3], a0o);
                    a1e = fmaf(c.x, w[4 * u4 + 0], a1e);
                    a1o = fmaf(c.y, w[4 * u4 + 1], a1o);
                    a1e = fmaf(c.z, w[4 * u4 + 2], a1e);
                    a1o = fmaf(c.w, w[4 * u4 + 3], a1o);
                }
                float iv0 = a0e + a0o + brec;
                float iv1 = a1e + a1o + brec;
                float xp0 = fmaf(xv0, k1g, bin);
                float xp1 = fmaf(xv1, k1g, bin);
                if (g < 2 * U1c) {  // z and r gates: pre-act = x-part + inner
                    zr1s[0][g] = xp0 + iv0;
                    zr1s[1][g] = xp1 + iv1;
                } else {            // h gate: keep x-part and inner separate
                    ih1s[0][g - 2 * U1c] = iv0;
                    ih1s[1][g - 2 * U1c] = iv1;
                    xh1s[0][g - 2 * U1c] = xp0;
                    xh1s[1][g - 2 * U1c] = xp1;
                }
            }
            __syncthreads();  // B1: gates visible

            if (t < NB * U1c && i < TT) {
                // h1 update: h = z*h + (1-z)*hh,  z/r = relu, hh = tanh
                const int b = t >> 7, j = t & (U1c - 1);
                float z  = fmaxf(zr1s[b][j], 0.0f);
                float r  = fmaxf(zr1s[b][U1c + j], 0.0f);
                float hh = tanhf(fmaf(r, ih1s[b][j], xh1s[b][j]));
                float h  = h1s[b][j];
                h1s[b][j] = fmaf(z, h - hh, hh);
            }
            if (t >= 256 && t < 256 + NB * U2c && i >= 1) {
                // h2 update (GRU2 is one step behind)
                const int tau = t - 256;
                const int b = tau >> 5, j = tau & (U2c - 1);
                float z  = sigmoidf_(zr2s[b][j]);
                float r  = sigmoidf_(zr2s[b][U2c + j]);
                float hh = fmaxf(fmaf(r, ih2s[b][j], xh2s[b][j]), 0.0f);
                float h  = h2s[b][j];
                h2s[b][j] = fmaf(z, h - hh, hh);
            }
            __syncthreads();  // B2: h updated
        }

        // ------------------------------------------------ dense head
        if (t < 2 * U2c) {
            const int b = t >> 5, j = t & (U2c - 1);
            float p = h2s[b][j] * wd[j];
#pragma unroll
            for (int m = 16; m >= 1; m >>= 1) p += __shfl_xor(p, m, 64);
            if ((t & (U2c - 1)) == 0) out[b0 + b] = p + bd[0];
        }
    } else {
        // ------------------------------------------------ GRU2 gate role
        const int ggr   = t - G1;          // 0..127 (96..127 are shadow lanes)
        const bool live = ggr < G2;
        const int gg    = live ? ggr : (G2 - 1);
        float wk[U1c];
#pragma unroll
        for (int u = 0; u < U1c; ++u) wk[u] = k2[u * G2 + gg];
        float wr[U2c];
#pragma unroll
        for (int u = 0; u < U2c; ++u) wr[u] = rk2[u * G2 + gg];
        const float bin2  = b2[gg];
        const float brec2 = b2[G2 + gg];

        __syncthreads();  // B0

        for (int i = 0; i <= TT; ++i) {
            if (i >= 1) {
                // gates for timestep i-1: uses h1(i-1) (=seq1[i-1]) and h2(i-2)
                float xe = 0.f, xo = 0.f;
                const float4* h40 = (const float4*)&h1s[0][0];
                const float4* h41 = (const float4*)&h1s[1][0];
                float x0e = 0.f, x0o = 0.f, x1e = 0.f, x1o = 0.f;
#pragma unroll
                for (int u4 = 0; u4 < U1c / 4; ++u4) {
                    float4 a = h40[u4];
                    float4 c = h41[u4];
                    x0e = fmaf(a.x, wk[4 * u4 + 0], x0e);
                    x0o = fmaf(a.y, wk[4 * u4 + 1], x0o);
                    x0e = fmaf(a.z, wk[4 * u4 + 2], x0e);
                    x0o = fmaf(a.w, wk[4 * u4 + 3], x0o);
                    x1e = fmaf(c.x, wk[4 * u4 + 0], x1e);
                    x1o = fmaf(c.y, wk[4 * u4 + 1], x1o);
                    x1e = fmaf(c.z, wk[4 * u4 + 2], x1e);
                    x1o = fmaf(c.w, wk[4 * u4 + 3], x1o);
                }
                float r0 = 0.f, r1 = 0.f;
                const float4* g40 = (const float4*)&h2s[0][0];
                const float4* g41 = (const float4*)&h2s[1][0];
#pragma unroll
                for (int u4 = 0; u4 < U2c / 4; ++u4) {
                    float4 a = g40[u4];
                    float4 c = g41[u4];
                    r0 = fmaf(a.x, wr[4 * u4 + 0], r0);
                    r0 = fmaf(a.y, wr[4 * u4 + 1], r0);
                    r0 = fmaf(a.z, wr[4 * u4 + 2], r0);
                    r0 = fmaf(a.w, wr[4 * u4 + 3], r0);
                    r1 = fmaf(c.x, wr[4 * u4 + 0], r1);
                    r1 = fmaf(c.y, wr[4 * u4 + 1], r1);
                    r1 = fmaf(c.z, wr[4 * u4 + 2], r1);
                    r1 = fmaf(c.w, wr[4 * u4 + 3], r1);
                }
                float xp0 = (x0e + x0o) + bin2;
                float xp1 = (x1e + x1o) + bin2;
                float iv0 = r0 + brec2;
                float iv1 = r1 + brec2;
                if (live) {
                    if (gg < 2 * U2c) {
                        zr2s[0][gg] = xp0 + iv0;
                        zr2s[1][gg] = xp1 + iv1;
                    } else {
                        ih2s[0][gg - 2 * U2c] = iv0;
                        ih2s[1][gg - 2 * U2c] = iv1;
                        xh2s[0][gg - 2 * U2c] = xp0;
                        xh2s[1][gg - 2 * U2c] = xp1;
                    }
                }
            }
            __syncthreads();  // B1
            // (updates handled by role-A threads)
            __syncthreads();  // B2
        }
    }
}

extern "C" void kernel_launch(void* const* d_in, const int* in_sizes, int n_in,
                              void* d_out, int out_size, void* d_ws, size_t ws_size,
                              hipStream_t stream) {
    const float* x   = (const float*)d_in[0];
    const float* k1  = (const float*)d_in[1];
    const float* rk1 = (const float*)d_in[2];
    const float* b1  = (const float*)d_in[3];
    const float* k2  = (const float*)d_in[4];
    const float* rk2 = (const float*)d_in[5];
    const float* b2  = (const float*)d_in[6];
    const float* wd  = (const float*)d_in[7];
    const float* bd  = (const float*)d_in[8];
    float* out = (float*)d_out;

    dim3 grid(256), block(512);
    hipLaunchKernelGGL(gru_stack_kernel, grid, block, 0, stream,
                       x, k1, rk1, b1, k2, rk2, b2, wd, bd, out);
}